// Round 14
// baseline (507.646 us; speedup 1.0000x reference)
//
#include <hip/hip_runtime.h>

// Problem constants: B=8, C=64, L=256, D=64, H=4, HD=16
typedef _Float16 f16;
typedef f16   f16x8 __attribute__((ext_vector_type(8)));
typedef float f32x4 __attribute__((ext_vector_type(4)));

#define MFMA(a,b,c) __builtin_amdgcn_mfma_f32_16x16x32_f16(a,b,c,0,0,0)

__device__ __forceinline__ f32x4 fz4(){ f32x4 z; z[0]=0.f; z[1]=0.f; z[2]=0.f; z[3]=0.f; return z; }
__device__ __forceinline__ f16x8 hz8(){ f16x8 z;
#pragma unroll
  for(int i=0;i<8;++i) z[i]=(f16)0.f;
  return z; }

#define NBLK 256u

// Device-scope sense-reversing grid barrier (r9/r10-proven).
__device__ __forceinline__ void grid_barrier(unsigned* bar) {
  __syncthreads();
  if (threadIdx.x == 0) {
    __threadfence();
    unsigned gen  = atomicAdd(&bar[1], 0u);
    unsigned prev = atomicAdd(&bar[0], 1u);
    if (prev == NBLK - 1u) {
      atomicExch(&bar[0], 0u);
      __threadfence();
      atomicAdd(&bar[1], 1u);
    } else {
      while (atomicAdd(&bar[1], 0u) == gen) __builtin_amdgcn_s_sleep(2);
    }
    __threadfence();
  }
  __syncthreads();
}

// ================= mega: EXACT r10 best (238.8 us) ==========================
__global__ __launch_bounds__(512, 2) void mega(
    const float* __restrict__ query, const float* __restrict__ key,
    const float* __restrict__ value,
    const float* __restrict__ Wq, const float* __restrict__ Wk,
    const float* __restrict__ Wv, const float* __restrict__ Wo,
    const float* __restrict__ bo, const float* __restrict__ gamma,
    const float* __restrict__ beta,
    f16* __restrict__ QKV, f16* __restrict__ AO,
    f16* WA, float* out, unsigned* bar)
{
  __shared__ f16 smem[32768];
  const int tid  = threadIdx.x;
  const int bid  = blockIdx.x;
  const int half = tid >> 8;
  const int ltid = tid & 255;
  const int lane = tid & 63;
  const int wvg  = tid >> 6;
  const int wvl  = (ltid >> 6);
  const int lr   = lane & 15, kh = lane >> 4;
  f16* hs = smem + half*16384;

  // phase 0: weight prepack (Q weights pre-scaled 0.25)
  {
    int gid = bid*512 + tid;
    if (gid < 110592) {
      int t = gid / 36864, r = gid % 36864;
      const float* W = (t==0)?Wq:((t==1)?Wk:Wv);
      float sc = (t==0) ? 0.25f : 1.0f;
      int kstep = r >> 11, rem = r & 2047;
      int co = rem >> 5, rem2 = rem & 31;
      int kq = rem2 >> 3, j = rem2 & 7;
      int k = kstep*32 + kq*8 + j;
      int sp = k >> 6, ci = k & 63;
      int ky = sp/3, kx = sp - ky*3;
      WA[gid] = (f16)(W[((co*64+ci)*3+ky)*3+kx]*sc);
    }
  }
  grid_barrier(bar);

  // phase 1: conv3x3, half-block per tile, 6 iters
  for (int iter = 0; iter < 6; ++iter) {
    int w    = bid + (iter*2 + half)*256;
    int b    = w & 7;
    int rest = w >> 3;
    int t    = rest >> 7;
    int l0   = (rest & 127) * 2;
    const float* X = (t==0)?query:((t==1)?key:value);
    const f16* WAt = WA + t*36864;
    f16* Yt = QKV + (size_t)t*8388608;
    {
      int ci0 = (ltid & 31)*2;
      int row = (ltid >> 5) & 3;
      int dh  = (ltid >> 7) * 32;
      int gr  = l0 - 1 + row;
      bool valid = (unsigned)gr < 256u;
      int grc = valid ? gr : 0;
      const f32x4* s0 = (const f32x4*)(X + (((size_t)(b*64+ci0  )*256 + grc)*64 + dh));
      const f32x4* s1 = (const f32x4*)(X + (((size_t)(b*64+ci0+1)*256 + grc)*64 + dh));
#pragma unroll
      for (int q=0;q<8;++q) {
        f32x4 f0 = valid ? s0[q] : fz4();
        f32x4 f1 = valid ? s1[q] : fz4();
#pragma unroll
        for (int e=0;e<4;++e) {
          int d = dh + q*4 + e;
          int idx = ((row*64 + d)*64 + ci0) ^ ((d&7)<<3);
          unsigned int pk = (unsigned int)__builtin_bit_cast(unsigned short,(f16)f0[e])
                          | ((unsigned int)__builtin_bit_cast(unsigned short,(f16)f1[e]) << 16);
          *(unsigned int*)&hs[idx] = pk;
        }
      }
    }
    __syncthreads();
    f32x4 acc[4][2];
#pragma unroll
    for (int mt=0;mt<4;++mt){ acc[mt][0]=fz4(); acc[mt][1]=fz4(); }
    for (int kstep=0; kstep<18; ++kstep) {
      int sp = kstep >> 1;
      int sp3 = sp/3;
      int dl = sp3 - 1;
      int dd = (sp - sp3*3) - 1;
      int cib = (kstep & 1)*32;
      const f16* wp = WAt + kstep*2048 + lr*32 + kh*8;
      f16x8 a0 = *(const f16x8*)(wp);
      f16x8 a1 = *(const f16x8*)(wp + 512);
      f16x8 a2 = *(const f16x8*)(wp + 1024);
      f16x8 a3 = *(const f16x8*)(wp + 1536);
      f16x8 bb[2];
#pragma unroll
      for (int nt=0;nt<2;++nt) {
        int n = wvl*32 + nt*16 + lr;
        int lloc = n >> 6, d = n & 63;
        int dp = d + dd;
        bool v = (unsigned)dp < 64u;
        int dpc = dp & 63;
        int rowi = lloc + dl + 1;
        int idx = ((rowi*64 + dpc)*64 + cib + kh*8) ^ ((dpc&7)<<3);
        f16x8 tt = *(const f16x8*)&hs[idx];
        if (!v) tt = hz8();
        bb[nt] = tt;
      }
#pragma unroll
      for (int nt=0;nt<2;++nt) {
        acc[0][nt] = MFMA(a0, bb[nt], acc[0][nt]);
        acc[1][nt] = MFMA(a1, bb[nt], acc[1][nt]);
        acc[2][nt] = MFMA(a2, bb[nt], acc[2][nt]);
        acc[3][nt] = MFMA(a3, bb[nt], acc[3][nt]);
      }
    }
#pragma unroll
    for (int mt=0;mt<4;++mt)
#pragma unroll
    for (int nt=0;nt<2;++nt)
#pragma unroll
    for (int r=0;r<4;++r) {
      int co = mt*16 + kh*4 + r;
      int n = wvl*32 + nt*16 + lr;
      int lrow = l0 + (n>>6), d = n & 63;
      Yt[((size_t)(b*64+co)*256 + lrow)*64 + d] = (f16)acc[mt][nt][r];
    }
    __syncthreads();
  }
  grid_barrier(bar);

  // phase 2: flash attention, 2 instances, 8 waves x 32 q-rows
  for (int k2 = 0; k2 < 2; ++k2) {
    int idx = bid + k2*256;
    int bc = (idx & 7)*64 + (idx >> 3);
    const f16* Qs = QKV + (size_t)bc*16384;
    const f16* Ks = QKV +  8388608 + (size_t)bc*16384;
    const f16* Vs = QKV + 16777216 + (size_t)bc*16384;
    __syncthreads();
    {
      int m  = tid & 63;
      int dg = (tid >> 6) * 8;
#pragma unroll
      for (int pass=0; pass<4; ++pass) {
        int mm = m + pass*64;
        f16x8 v0 = *(const f16x8*)(Vs + mm*64 + dg);
#pragma unroll
        for (int e=0;e<8;++e){ int d=dg+e; smem[(d*256+mm) ^ ((d&7)<<3)] = v0[e]; }
      }
    }
    int l0g = wvg*32;
    f16x8 qf[2][2];
#pragma unroll
    for (int lt=0;lt<2;++lt)
#pragma unroll
    for (int ks=0;ks<2;++ks)
      qf[lt][ks] = *(const f16x8*)(Qs + (l0g + lt*16 + lr)*64 + ks*32 + kh*8);
    f32x4 O[2][4];
    float rm[2][4], rl[2][4];
#pragma unroll
    for (int lt=0;lt<2;++lt)
#pragma unroll
    for (int x=0;x<4;++x) { O[lt][x]=fz4(); rm[lt][x]=-1e30f; rl[lt][x]=0.f; }
    __syncthreads();
    f16* P = &smem[16384 + wvg*2048];
    for (int it=0; it<4; ++it) {
      int m0 = it*64;
      f32x4 s[2][4];
#pragma unroll
      for (int lt=0;lt<2;++lt)
#pragma unroll
      for (int mt=0;mt<4;++mt) s[lt][mt]=fz4();
#pragma unroll
      for (int ks=0;ks<2;++ks) {
        f16x8 kf[4];
#pragma unroll
        for (int mt=0;mt<4;++mt)
          kf[mt] = *(const f16x8*)(Ks + (m0 + mt*16 + lr)*64 + ks*32 + kh*8);
#pragma unroll
        for (int lt=0;lt<2;++lt)
#pragma unroll
        for (int mt=0;mt<4;++mt)
          s[lt][mt] = MFMA(qf[lt][ks], kf[mt], s[lt][mt]);
      }
#pragma unroll
      for (int lt=0;lt<2;++lt)
#pragma unroll
      for (int r=0;r<4;++r) {
        float tm = fmaxf(fmaxf(s[lt][0][r], s[lt][1][r]), fmaxf(s[lt][2][r], s[lt][3][r]));
#pragma unroll
        for (int off=1; off<16; off<<=1) tm = fmaxf(tm, __shfl_xor(tm, off));
        float mo = rm[lt][r];
        float mn = fmaxf(mo, tm);
        rm[lt][r] = mn;
        float corr = __expf(mo - mn);
        float sum = 0.f;
#pragma unroll
        for (int mt=0;mt<4;++mt) { float p = __expf(s[lt][mt][r] - mn); s[lt][mt][r] = p; sum += p; }
#pragma unroll
        for (int off=1; off<16; off<<=1) sum += __shfl_xor(sum, off);
        rl[lt][r] = rl[lt][r]*corr + sum;
#pragma unroll
        for (int dt=0;dt<4;++dt) O[lt][dt][r] *= corr;
      }
#pragma unroll
      for (int lt=0;lt<2;++lt)
#pragma unroll
      for (int mt=0;mt<4;++mt)
#pragma unroll
      for (int r=0;r<4;++r) {
        int row = lt*16 + kh*4 + r;
        P[(row*64 + mt*16 + lr) ^ ((row&7)<<3)] = (f16)s[lt][mt][r];
      }
#pragma unroll
      for (int ks=0;ks<2;++ks) {
        f16x8 pa[2], vb[4];
#pragma unroll
        for (int lt=0;lt<2;++lt) {
          int row = lt*16 + lr;
          pa[lt] = *(const f16x8*)&P[(row*64 + ks*32 + kh*8) ^ ((row&7)<<3)];
        }
#pragma unroll
        for (int dt=0;dt<4;++dt) {
          int d = dt*16 + lr;
          vb[dt] = *(const f16x8*)&smem[(d*256 + m0 + ks*32 + kh*8) ^ ((d&7)<<3)];
        }
#pragma unroll
        for (int lt=0;lt<2;++lt)
#pragma unroll
        for (int dt=0;dt<4;++dt)
          O[lt][dt] = MFMA(pa[lt], vb[dt], O[lt][dt]);
      }
    }
#pragma unroll
    for (int lt=0;lt<2;++lt)
#pragma unroll
    for (int r=0;r<4;++r) {
      float inv = 1.f / rl[lt][r];
      int row = l0g + lt*16 + kh*4 + r;
#pragma unroll
      for (int dt=0;dt<4;++dt)
        AO[(size_t)bc*16384 + row*64 + dt*16 + lr] = (f16)(O[lt][dt][r]*inv);
    }
  }
  grid_barrier(bar);

  // phase 3: 1x1 conv + bias + residual + LN
  for (int iter = 0; iter < 2; ++iter) {
    int w  = bid + (iter*2 + half)*256;
    int b  = w & 7;
    int p0 = (w >> 3) * 128;
    {
      int ci = ltid & 63;
      int pg = ltid >> 6;
      const f16* src = AO + (size_t)(b*64+ci)*16384 + p0 + pg*32;
      f16x8 v[4];
#pragma unroll
      for (int q=0;q<4;++q) v[q] = *(const f16x8*)(src + q*8);
#pragma unroll
      for (int q=0;q<4;++q)
#pragma unroll
      for (int e=0;e<8;++e) {
        int p = pg*32 + q*8 + e;
        hs[(p*64 + ci) ^ ((p&7)<<3)] = v[q][e];
      }
      int co  = ltid >> 2;
      int cig = (ltid & 3) * 16;
      const f32x4* wsrc = (const f32x4*)(Wo + co*64 + cig);
      f32x4 w0 = wsrc[0], w1 = wsrc[1], w2 = wsrc[2], w3 = wsrc[3];
      f16x8 g0, g1;
#pragma unroll
      for (int e=0;e<4;++e) { g0[e]=(f16)w0[e]; g0[4+e]=(f16)w1[e]; g1[e]=(f16)w2[e]; g1[4+e]=(f16)w3[e]; }
      *(f16x8*)&hs[8192 + ((co*64 + cig    ) ^ ((co&7)<<3))] = g0;
      *(f16x8*)&hs[8192 + ((co*64 + cig + 8) ^ ((co&7)<<3))] = g1;
    }
    __syncthreads();
    int n0 = wvl*32;
    f32x4 acc[4][2];
#pragma unroll
    for (int mt=0;mt<4;++mt){ acc[mt][0]=fz4(); acc[mt][1]=fz4(); }
#pragma unroll
    for (int ks=0;ks<2;++ks) {
      f16x8 a[4], bb[2];
#pragma unroll
      for (int mt=0;mt<4;++mt)
        a[mt] = *(const f16x8*)&hs[8192 + (((mt*16+lr)*64 + ks*32 + kh*8) ^ ((lr&7)<<3))];
#pragma unroll
      for (int nt=0;nt<2;++nt) {
        int p = n0 + nt*16 + lr;
        bb[nt] = *(const f16x8*)&hs[(p*64 + ks*32 + kh*8) ^ ((p&7)<<3)];
      }
#pragma unroll
      for (int mt=0;mt<4;++mt)
#pragma unroll
      for (int nt=0;nt<2;++nt)
        acc[mt][nt] = MFMA(a[mt], bb[nt], acc[mt][nt]);
    }
    float vals[4][2][4];
    float sum0=0.f, sq0=0.f, sum1=0.f, sq1=0.f;
#pragma unroll
    for (int mt=0;mt<4;++mt)
#pragma unroll
    for (int nt=0;nt<2;++nt)
#pragma unroll
    for (int r=0;r<4;++r) {
      int co = mt*16 + kh*4 + r;
      int p  = p0 + n0 + nt*16 + lr;
      float v = acc[mt][nt][r] + bo[co] + query[(size_t)(b*64+co)*16384 + p];
      vals[mt][nt][r] = v;
      if (nt==0) { sum0 += v; sq0 += v*v; } else { sum1 += v; sq1 += v*v; }
    }
#pragma unroll
    for (int off=16; off<64; off<<=1) {
      sum0 += __shfl_xor(sum0, off); sq0 += __shfl_xor(sq0, off);
      sum1 += __shfl_xor(sum1, off); sq1 += __shfl_xor(sq1, off);
    }
    float mu0 = sum0*(1.f/64.f), var0 = sq0*(1.f/64.f) - mu0*mu0, rs0 = rsqrtf(var0 + 1e-5f);
    float mu1 = sum1*(1.f/64.f), var1 = sq1*(1.f/64.f) - mu1*mu1, rs1 = rsqrtf(var1 + 1e-5f);
#pragma unroll
    for (int mt=0;mt<4;++mt)
#pragma unroll
    for (int nt=0;nt<2;++nt)
#pragma unroll
    for (int r=0;r<4;++r) {
      int co = mt*16 + kh*4 + r;
      int p  = p0 + n0 + nt*16 + lr;
      float mu = nt ? mu1 : mu0;
      float rs = nt ? rs1 : rs0;
      out[(size_t)(b*64+co)*16384 + p] = (vals[mt][nt][r] - mu)*rs*gamma[co] + beta[co];
    }
    __syncthreads();
  }
}

// ================= PROBES (instrumentation only; never touch d_out) =========
// probe_prep: WAp = AO-region head (AO dead after mega).
__global__ __launch_bounds__(256) void probe_prep(
    const float* __restrict__ Wq, const float* __restrict__ Wk,
    const float* __restrict__ Wv, f16* __restrict__ WAp)
{
  int gid = blockIdx.x*256 + threadIdx.x;
  if (gid < 110592) {
    int t = gid / 36864, r = gid % 36864;
    const float* W = (t==0)?Wq:((t==1)?Wk:Wv);
    float sc = (t==0) ? 0.25f : 1.0f;
    int kstep = r >> 11, rem = r & 2047;
    int co = rem >> 5, rem2 = rem & 31;
    int kq = rem2 >> 3, j = rem2 & 7;
    int k = kstep*32 + kq*8 + j;
    int sp = k >> 6, ci = k & 63;
    int ky = sp/3, kx = sp - ky*3;
    WAp[gid] = (f16)(W[((co*64+ci)*3+ky)*3+kx]*sc);
  }
}

// probe_conv_mega: mega's phase-1 structure standalone (256x512, 6 iters).
__global__ __launch_bounds__(512, 2) void probe_conv_mega(
    const float* __restrict__ query, const float* __restrict__ key,
    const float* __restrict__ value, const f16* __restrict__ WAp,
    f16* __restrict__ QKV)
{
  __shared__ f16 smem[32768];
  const int tid  = threadIdx.x;
  const int bid  = blockIdx.x;
  const int half = tid >> 8;
  const int ltid = tid & 255;
  const int lane = tid & 63;
  const int wvl  = (ltid >> 6);
  const int lr   = lane & 15, kh = lane >> 4;
  f16* hs = smem + half*16384;
  for (int iter = 0; iter < 6; ++iter) {
    int w    = bid + (iter*2 + half)*256;
    int b    = w & 7;
    int rest = w >> 3;
    int t    = rest >> 7;
    int l0   = (rest & 127) * 2;
    const float* X = (t==0)?query:((t==1)?key:value);
    const f16* WAt = WAp + t*36864;
    f16* Yt = QKV + (size_t)t*8388608;
    {
      int ci0 = (ltid & 31)*2;
      int row = (ltid >> 5) & 3;
      int dh  = (ltid >> 7) * 32;
      int gr  = l0 - 1 + row;
      bool valid = (unsigned)gr < 256u;
      int grc = valid ? gr : 0;
      const f32x4* s0 = (const f32x4*)(X + (((size_t)(b*64+ci0  )*256 + grc)*64 + dh));
      const f32x4* s1 = (const f32x4*)(X + (((size_t)(b*64+ci0+1)*256 + grc)*64 + dh));
#pragma unroll
      for (int q=0;q<8;++q) {
        f32x4 f0 = valid ? s0[q] : fz4();
        f32x4 f1 = valid ? s1[q] : fz4();
#pragma unroll
        for (int e=0;e<4;++e) {
          int d = dh + q*4 + e;
          int idx = ((row*64 + d)*64 + ci0) ^ ((d&7)<<3);
          unsigned int pk = (unsigned int)__builtin_bit_cast(unsigned short,(f16)f0[e])
                          | ((unsigned int)__builtin_bit_cast(unsigned short,(f16)f1[e]) << 16);
          *(unsigned int*)&hs[idx] = pk;
        }
      }
    }
    __syncthreads();
    f32x4 acc[4][2];
#pragma unroll
    for (int mt=0;mt<4;++mt){ acc[mt][0]=fz4(); acc[mt][1]=fz4(); }
    for (int kstep=0; kstep<18; ++kstep) {
      int sp = kstep >> 1;
      int sp3 = sp/3;
      int dl = sp3 - 1;
      int dd = (sp - sp3*3) - 1;
      int cib = (kstep & 1)*32;
      const f16* wp = WAt + kstep*2048 + lr*32 + kh*8;
      f16x8 a0 = *(const f16x8*)(wp);
      f16x8 a1 = *(const f16x8*)(wp + 512);
      f16x8 a2 = *(const f16x8*)(wp + 1024);
      f16x8 a3 = *(const f16x8*)(wp + 1536);
      f16x8 bb[2];
#pragma unroll
      for (int nt=0;nt<2;++nt) {
        int n = wvl*32 + nt*16 + lr;
        int lloc = n >> 6, d = n & 63;
        int dp = d + dd;
        bool v = (unsigned)dp < 64u;
        int dpc = dp & 63;
        int rowi = lloc + dl + 1;
        int idx = ((rowi*64 + dpc)*64 + cib + kh*8) ^ ((dpc&7)<<3);
        f16x8 tt = *(const f16x8*)&hs[idx];
        if (!v) tt = hz8();
        bb[nt] = tt;
      }
#pragma unroll
      for (int nt=0;nt<2;++nt) {
        acc[0][nt] = MFMA(a0, bb[nt], acc[0][nt]);
        acc[1][nt] = MFMA(a1, bb[nt], acc[1][nt]);
        acc[2][nt] = MFMA(a2, bb[nt], acc[2][nt]);
        acc[3][nt] = MFMA(a3, bb[nt], acc[3][nt]);
      }
    }
#pragma unroll
    for (int mt=0;mt<4;++mt)
#pragma unroll
    for (int nt=0;nt<2;++nt)
#pragma unroll
    for (int r=0;r<4;++r) {
      int co = mt*16 + kh*4 + r;
      int n = wvl*32 + nt*16 + lr;
      int lrow = l0 + (n>>6), d = n & 63;
      Yt[((size_t)(b*64+co)*256 + lrow)*64 + d] = (f16)acc[mt][nt][r];
    }
    __syncthreads();
  }
}

// probe_conv_wide: same conv as ONE dispatch, 3072 blocks x 256 (12 blk/CU TLP).
__global__ __launch_bounds__(256) void probe_conv_wide(
    const float* __restrict__ query, const float* __restrict__ key,
    const float* __restrict__ value, const f16* __restrict__ WAp,
    f16* __restrict__ QKV)
{
  __shared__ f16 hs[16384];
  int b    = blockIdx.x & 7;
  int rest = blockIdx.x >> 3;
  int t    = rest >> 7;
  int l0   = (rest & 127) * 2;
  const float* X = (t==0)?query:((t==1)?key:value);
  const f16* WAt = WAp + t*36864;
  f16* Yt = QKV + (size_t)t*8388608;
  int tid = threadIdx.x;
  int lane = tid & 63, wvl = tid >> 6;
  int lr = lane & 15, kh = lane >> 4;
  {
    int ci0 = (tid & 31)*2;
    int row = (tid >> 5) & 3;
    int dh  = (tid >> 7) * 32;
    int gr  = l0 - 1 + row;
    bool valid = (unsigned)gr < 256u;
    int grc = valid ? gr : 0;
    const f32x4* s0 = (const f32x4*)(X + (((size_t)(b*64+ci0  )*256 + grc)*64 + dh));
    const f32x4* s1 = (const f32x4*)(X + (((size_t)(b*64+ci0+1)*256 + grc)*64 + dh));
#pragma unroll
    for (int q=0;q<8;++q) {
      f32x4 f0 = valid ? s0[q] : fz4();
      f32x4 f1 = valid ? s1[q] : fz4();
#pragma unroll
      for (int e=0;e<4;++e) {
        int d = dh + q*4 + e;
        int idx = ((row*64 + d)*64 + ci0) ^ ((d&7)<<3);
        unsigned int pk = (unsigned int)__builtin_bit_cast(unsigned short,(f16)f0[e])
                        | ((unsigned int)__builtin_bit_cast(unsigned short,(f16)f1[e]) << 16);
        *(unsigned int*)&hs[idx] = pk;
      }
    }
  }
  __syncthreads();
  f32x4 acc[4][2];
#pragma unroll
  for (int mt=0;mt<4;++mt){ acc[mt][0]=fz4(); acc[mt][1]=fz4(); }
  for (int kstep=0; kstep<18; ++kstep) {
    int sp = kstep >> 1;
    int sp3 = sp/3;
    int dl = sp3 - 1;
    int dd = (sp - sp3*3) - 1;
    int cib = (kstep & 1)*32;
    const f16* wp = WAt + kstep*2048 + lr*32 + kh*8;
    f16x8 a0 = *(const f16x8*)(wp);
    f16x8 a1 = *(const f16x8*)(wp + 512);
    f16x8 a2 = *(const f16x8*)(wp + 1024);
    f16x8 a3 = *(const f16x8*)(wp + 1536);
    f16x8 bb[2];
#pragma unroll
    for (int nt=0;nt<2;++nt) {
      int n = wvl*32 + nt*16 + lr;
      int lloc = n >> 6, d = n & 63;
      int dp = d + dd;
      bool v = (unsigned)dp < 64u;
      int dpc = dp & 63;
      int rowi = lloc + dl + 1;
      int idx = ((rowi*64 + dpc)*64 + cib + kh*8) ^ ((dpc&7)<<3);
      f16x8 tt = *(const f16x8*)&hs[idx];
      if (!v) tt = hz8();
      bb[nt] = tt;
    }
#pragma unroll
    for (int nt=0;nt<2;++nt) {
      acc[0][nt] = MFMA(a0, bb[nt], acc[0][nt]);
      acc[1][nt] = MFMA(a1, bb[nt], acc[1][nt]);
      acc[2][nt] = MFMA(a2, bb[nt], acc[2][nt]);
      acc[3][nt] = MFMA(a3, bb[nt], acc[3][nt]);
    }
  }
#pragma unroll
  for (int mt=0;mt<4;++mt)
#pragma unroll
  for (int nt=0;nt<2;++nt)
#pragma unroll
  for (int r=0;r<4;++r) {
    int co = mt*16 + kh*4 + r;
    int n = wvl*32 + nt*16 + lr;
    int lrow = l0 + (n>>6), d = n & 63;
    Yt[((size_t)(b*64+co)*256 + lrow)*64 + d] = (f16)acc[mt][nt][r];
  }
}

// probe_attn: mega's phase-2 standalone (256x512).
__global__ __launch_bounds__(512, 2) void probe_attn(
    const f16* __restrict__ QKV, f16* __restrict__ AOp)
{
  __shared__ f16 smem[32768];
  int tid = threadIdx.x, bid = blockIdx.x;
  int lane = tid & 63, wvg = tid >> 6;
  int lr = lane & 15, kh = lane >> 4;
  for (int k2 = 0; k2 < 2; ++k2) {
    int idx = bid + k2*256;
    int bc = (idx & 7)*64 + (idx >> 3);
    const f16* Qs = QKV + (size_t)bc*16384;
    const f16* Ks = QKV +  8388608 + (size_t)bc*16384;
    const f16* Vs = QKV + 16777216 + (size_t)bc*16384;
    __syncthreads();
    {
      int m  = tid & 63;
      int dg = (tid >> 6) * 8;
#pragma unroll
      for (int pass=0; pass<4; ++pass) {
        int mm = m + pass*64;
        f16x8 v0 = *(const f16x8*)(Vs + mm*64 + dg);
#pragma unroll
        for (int e=0;e<8;++e){ int d=dg+e; smem[(d*256+mm) ^ ((d&7)<<3)] = v0[e]; }
      }
    }
    int l0g = wvg*32;
    f16x8 qf[2][2];
#pragma unroll
    for (int lt=0;lt<2;++lt)
#pragma unroll
    for (int ks=0;ks<2;++ks)
      qf[lt][ks] = *(const f16x8*)(Qs + (l0g + lt*16 + lr)*64 + ks*32 + kh*8);
    f32x4 O[2][4];
    float rm[2][4], rl[2][4];
#pragma unroll
    for (int lt=0;lt<2;++lt)
#pragma unroll
    for (int x=0;x<4;++x) { O[lt][x]=fz4(); rm[lt][x]=-1e30f; rl[lt][x]=0.f; }
    __syncthreads();
    f16* P = &smem[16384 + wvg*2048];
    for (int it=0; it<4; ++it) {
      int m0 = it*64;
      f32x4 s[2][4];
#pragma unroll
      for (int lt=0;lt<2;++lt)
#pragma unroll
      for (int mt=0;mt<4;++mt) s[lt][mt]=fz4();
#pragma unroll
      for (int ks=0;ks<2;++ks) {
        f16x8 kf[4];
#pragma unroll
        for (int mt=0;mt<4;++mt)
          kf[mt] = *(const f16x8*)(Ks + (m0 + mt*16 + lr)*64 + ks*32 + kh*8);
#pragma unroll
        for (int lt=0;lt<2;++lt)
#pragma unroll
        for (int mt=0;mt<4;++mt)
          s[lt][mt] = MFMA(qf[lt][ks], kf[mt], s[lt][mt]);
      }
#pragma unroll
      for (int lt=0;lt<2;++lt)
#pragma unroll
      for (int r=0;r<4;++r) {
        float tm = fmaxf(fmaxf(s[lt][0][r], s[lt][1][r]), fmaxf(s[lt][2][r], s[lt][3][r]));
#pragma unroll
        for (int off=1; off<16; off<<=1) tm = fmaxf(tm, __shfl_xor(tm, off));
        float mo = rm[lt][r];
        float mn = fmaxf(mo, tm);
        rm[lt][r] = mn;
        float corr = __expf(mo - mn);
        float sum = 0.f;
#pragma unroll
        for (int mt=0;mt<4;++mt) { float p = __expf(s[lt][mt][r] - mn); s[lt][mt][r] = p; sum += p; }
#pragma unroll
        for (int off=1; off<16; off<<=1) sum += __shfl_xor(sum, off);
        rl[lt][r] = rl[lt][r]*corr + sum;
#pragma unroll
        for (int dt=0;dt<4;++dt) O[lt][dt][r] *= corr;
      }
#pragma unroll
      for (int lt=0;lt<2;++lt)
#pragma unroll
      for (int mt=0;mt<4;++mt)
#pragma unroll
      for (int r=0;r<4;++r) {
        int row = lt*16 + kh*4 + r;
        P[(row*64 + mt*16 + lr) ^ ((row&7)<<3)] = (f16)s[lt][mt][r];
      }
#pragma unroll
      for (int ks=0;ks<2;++ks) {
        f16x8 pa[2], vb[4];
#pragma unroll
        for (int lt=0;lt<2;++lt) {
          int row = lt*16 + lr;
          pa[lt] = *(const f16x8*)&P[(row*64 + ks*32 + kh*8) ^ ((row&7)<<3)];
        }
#pragma unroll
        for (int dt=0;dt<4;++dt) {
          int d = dt*16 + lr;
          vb[dt] = *(const f16x8*)&smem[(d*256 + m0 + ks*32 + kh*8) ^ ((d&7)<<3)];
        }
#pragma unroll
        for (int lt=0;lt<2;++lt)
#pragma unroll
        for (int dt=0;dt<4;++dt)
          O[lt][dt] = MFMA(pa[lt], vb[dt], O[lt][dt]);
      }
    }
#pragma unroll
    for (int lt=0;lt<2;++lt)
#pragma unroll
    for (int r=0;r<4;++r) {
      float inv = 1.f / rl[lt][r];
      int row = l0g + lt*16 + kh*4 + r;
#pragma unroll
      for (int dt=0;dt<4;++dt)
        AOp[(size_t)bc*16384 + row*64 + dt*16 + lr] = (f16)(O[lt][dt][r]*inv);
    }
  }
}

// probe_proj: mega's phase-3 standalone (256x512), writes pout (ws, not d_out).
__global__ __launch_bounds__(512, 2) void probe_proj(
    const f16* __restrict__ AOp, const float* __restrict__ Wo,
    const float* __restrict__ bo, const float* __restrict__ gamma,
    const float* __restrict__ beta, const float* __restrict__ query,
    float* __restrict__ pout)
{
  __shared__ f16 smem[32768];
  int tid = threadIdx.x, bid = blockIdx.x;
  int half = tid >> 8, ltid = tid & 255;
  int lane = tid & 63, wvl = (ltid >> 6);
  int lr = lane & 15, kh = lane >> 4;
  f16* hs = smem + half*16384;
  for (int iter = 0; iter < 2; ++iter) {
    int w  = bid + (iter*2 + half)*256;
    int b  = w & 7;
    int p0 = (w >> 3) * 128;
    {
      int ci = ltid & 63;
      int pg = ltid >> 6;
      const f16* src = AOp + (size_t)(b*64+ci)*16384 + p0 + pg*32;
      f16x8 v[4];
#pragma unroll
      for (int q=0;q<4;++q) v[q] = *(const f16x8*)(src + q*8);
#pragma unroll
      for (int q=0;q<4;++q)
#pragma unroll
      for (int e=0;e<8;++e) {
        int p = pg*32 + q*8 + e;
        hs[(p*64 + ci) ^ ((p&7)<<3)] = v[q][e];
      }
      int co  = ltid >> 2;
      int cig = (ltid & 3) * 16;
      const f32x4* wsrc = (const f32x4*)(Wo + co*64 + cig);
      f32x4 w0 = wsrc[0], w1 = wsrc[1], w2 = wsrc[2], w3 = wsrc[3];
      f16x8 g0, g1;
#pragma unroll
      for (int e=0;e<4;++e) { g0[e]=(f16)w0[e]; g0[4+e]=(f16)w1[e]; g1[e]=(f16)w2[e]; g1[4+e]=(f16)w3[e]; }
      *(f16x8*)&hs[8192 + ((co*64 + cig    ) ^ ((co&7)<<3))] = g0;
      *(f16x8*)&hs[8192 + ((co*64 + cig + 8) ^ ((co&7)<<3))] = g1;
    }
    __syncthreads();
    int n0 = wvl*32;
    f32x4 acc[4][2];
#pragma unroll
    for (int mt=0;mt<4;++mt){ acc[mt][0]=fz4(); acc[mt][1]=fz4(); }
#pragma unroll
    for (int ks=0;ks<2;++ks) {
      f16x8 a[4], bb[2];
#pragma unroll
      for (int mt=0;mt<4;++mt)
        a[mt] = *(const f16x8*)&hs[8192 + (((mt*16+lr)*64 + ks*32 + kh*8) ^ ((lr&7)<<3))];
#pragma unroll
      for (int nt=0;nt<2;++nt) {
        int p = n0 + nt*16 + lr;
        bb[nt] = *(const f16x8*)&hs[(p*64 + ks*32 + kh*8) ^ ((p&7)<<3)];
      }
#pragma unroll
      for (int mt=0;mt<4;++mt)
#pragma unroll
      for (int nt=0;nt<2;++nt)
        acc[mt][nt] = MFMA(a[mt], bb[nt], acc[mt][nt]);
    }
    float vals[4][2][4];
    float sum0=0.f, sq0=0.f, sum1=0.f, sq1=0.f;
#pragma unroll
    for (int mt=0;mt<4;++mt)
#pragma unroll
    for (int nt=0;nt<2;++nt)
#pragma unroll
    for (int r=0;r<4;++r) {
      int co = mt*16 + kh*4 + r;
      int p  = p0 + n0 + nt*16 + lr;
      float v = acc[mt][nt][r] + bo[co] + query[(size_t)(b*64+co)*16384 + p];
      vals[mt][nt][r] = v;
      if (nt==0) { sum0 += v; sq0 += v*v; } else { sum1 += v; sq1 += v*v; }
    }
#pragma unroll
    for (int off=16; off<64; off<<=1) {
      sum0 += __shfl_xor(sum0, off); sq0 += __shfl_xor(sq0, off);
      sum1 += __shfl_xor(sum1, off); sq1 += __shfl_xor(sq1, off);
    }
    float mu0 = sum0*(1.f/64.f), var0 = sq0*(1.f/64.f) - mu0*mu0, rs0 = rsqrtf(var0 + 1e-5f);
    float mu1 = sum1*(1.f/64.f), var1 = sq1*(1.f/64.f) - mu1*mu1, rs1 = rsqrtf(var1 + 1e-5f);
#pragma unroll
    for (int mt=0;mt<4;++mt)
#pragma unroll
    for (int nt=0;nt<2;++nt)
#pragma unroll
    for (int r=0;r<4;++r) {
      int co = mt*16 + kh*4 + r;
      int p  = p0 + n0 + nt*16 + lr;
      float mu = nt ? mu1 : mu0;
      float rs = nt ? rs1 : rs0;
      pout[(size_t)(b*64+co)*16384 + p] = (vals[mt][nt][r] - mu)*rs*gamma[co] + beta[co];
    }
    __syncthreads();
  }
}

extern "C" void kernel_launch(void* const* d_in, const int* in_sizes, int n_in,
                              void* d_out, int out_size, void* d_ws, size_t ws_size,
                              hipStream_t stream)
{
  const float* query = (const float*)d_in[0];
  const float* key   = (const float*)d_in[1];
  const float* value = (const float*)d_in[2];
  const float* Wq = (const float*)d_in[3];
  const float* Wk = (const float*)d_in[4];
  const float* Wv = (const float*)d_in[5];
  const float* Wo = (const float*)d_in[6];
  const float* bo = (const float*)d_in[7];
  const float* gamma = (const float*)d_in[8];
  const float* beta  = (const float*)d_in[9];
  char* ws = (char*)d_ws;
  // ws: QKV [0,48MiB) | AO [48,64MiB). d_out head: WA scratch + bar at +1MiB.
  f16*      QKV  = (f16*)ws;
  f16*      AO   = (f16*)(ws + (size_t)50331648);
  f16*      WA   = (f16*)d_out;
  float*    outp = (float*)d_out;
  unsigned* bar  = (unsigned*)((char*)d_out + (size_t)(1<<20));

  hipMemsetAsync(bar, 0, 64, stream);
  // Real computation (exact r10 best). Output = d_out, final.
  mega<<<dim3(NBLK), dim3(512), 0, stream>>>(
      query, key, value, Wq, Wk, Wv, Wo, bo, gamma, beta,
      QKV, AO, WA, outp, bar);

  // ---- instrumentation probes: per-phase timing via rocprof dispatches. ----
  // They only read inputs/ws and write ws (all regions written earlier in this
  // same call) — d_out is untouched, output stays deterministic.
  f16*   WAp  = AO;                       // AO region head (dead after mega)
  f16*   AOp  = AO;                       // attn probe rewrites AO region
  float* pout = (float*)QKV;              // proj probe writes into QKV region
  probe_prep<<<432, 256, 0, stream>>>(Wq, Wk, Wv, WAp);
  probe_conv_mega<<<dim3(NBLK), dim3(512), 0, stream>>>(query, key, value, WAp, QKV);
  probe_conv_wide<<<3072, 256, 0, stream>>>(query, key, value, WAp, QKV);
  probe_attn<<<dim3(NBLK), dim3(512), 0, stream>>>(QKV, AOp);
  probe_proj<<<dim3(NBLK), dim3(512), 0, stream>>>(AOp, Wo, bo, gamma, beta, query, pout);
}

// Round 15
// 334.924 us; speedup vs baseline: 1.5157x; 1.5157x over previous
//
#include <hip/hip_runtime.h>

// Problem constants: B=8, C=64, L=256, D=64, H=4, HD=16
typedef _Float16 f16;
typedef f16   f16x8 __attribute__((ext_vector_type(8)));
typedef float f32x4 __attribute__((ext_vector_type(4)));

#define MFMA(a,b,c) __builtin_amdgcn_mfma_f32_16x16x32_f16(a,b,c,0,0,0)

__device__ __forceinline__ f32x4 fz4(){ f32x4 z; z[0]=0.f; z[1]=0.f; z[2]=0.f; z[3]=0.f; return z; }
__device__ __forceinline__ f16x8 hz8(){ f16x8 z;
#pragma unroll
  for(int i=0;i<8;++i) z[i]=(f16)0.f;
  return z; }

// Device-scope sense-reversing grid barrier (r9/r10-proven), runtime block count.
__device__ __forceinline__ void grid_barrier(unsigned* bar, unsigned nblk) {
  __syncthreads();
  if (threadIdx.x == 0) {
    __threadfence();
    unsigned gen  = atomicAdd(&bar[1], 0u);
    unsigned prev = atomicAdd(&bar[0], 1u);
    if (prev == nblk - 1u) {
      atomicExch(&bar[0], 0u);
      __threadfence();
      atomicAdd(&bar[1], 1u);
    } else {
      while (atomicAdd(&bar[1], 0u) == gen) __builtin_amdgcn_s_sleep(2);
    }
    __threadfence();
  }
  __syncthreads();
}

// ONE kernel, nblk x 512 threads. nblk=512 -> 2 blocks/CU (16 waves/CU with
// full r10 tile geometry and <=128 VGPR); nblk=256 -> r10-proven fallback.
// Host picks nblk via hipOccupancyMaxActiveBlocksPerMultiprocessor.
// Phases: prep -> conv(QKV) -> attention -> proj+LN, grid-barrier separated.
__global__ __launch_bounds__(512, 4) void mega(
    const float* __restrict__ query, const float* __restrict__ key,
    const float* __restrict__ value,
    const float* __restrict__ Wq, const float* __restrict__ Wk,
    const float* __restrict__ Wv, const float* __restrict__ Wo,
    const float* __restrict__ bo, const float* __restrict__ gamma,
    const float* __restrict__ beta,
    f16* __restrict__ QKV, f16* __restrict__ AO,
    f16* WA, float* out, unsigned* bar, unsigned nblk)
{
  __shared__ f16 smem[32768];   // 64 KiB (2 blocks/CU -> 128 of 160 KiB)
  const int tid  = threadIdx.x;
  const int bid  = blockIdx.x;
  const int half = tid >> 8;
  const int ltid = tid & 255;
  const int lane = tid & 63;
  const int wvg  = tid >> 6;
  const int wvl  = (ltid >> 6);
  const int lr   = lane & 15, kh = lane >> 4;
  f16* hs = smem + half*16384;

  // phase 0: weight prepack (Q weights pre-scaled 0.25 = 1/sqrt(HD))
  // WA[tensor][kstep(18)][co(64)][kq(4)][j(8)], k=kstep*32+kq*8+j=(ky*3+kx)*64+ci
  {
    int gid = bid*512 + tid;
    if (gid < 110592) {
      int t = gid / 36864, r = gid % 36864;
      const float* W = (t==0)?Wq:((t==1)?Wk:Wv);
      float sc = (t==0) ? 0.25f : 1.0f;
      int kstep = r >> 11, rem = r & 2047;
      int co = rem >> 5, rem2 = rem & 31;
      int kq = rem2 >> 3, j = rem2 & 7;
      int k = kstep*32 + kq*8 + j;
      int sp = k >> 6, ci = k & 63;
      int ky = sp/3, kx = sp - ky*3;
      WA[gid] = (f16)(W[((co*64+ci)*3+ky)*3+kx]*sc);
    }
  }
  grid_barrier(bar, nblk);

  // phase 1: conv3x3 as implicit GEMM, half-block per tile.
  // tiles = 3072; iters = 3072/(2*nblk). w & 7 == bid & 7 (XCD-local X slice).
  {
    int iters = 3072 / (2*(int)nblk);
    for (int iter = 0; iter < iters; ++iter) {
      int w    = bid + (iter*2 + half)*(int)nblk;
      int b    = w & 7;
      int rest = w >> 3;
      int t    = rest >> 7;
      int l0   = (rest & 127) * 2;
      const float* X = (t==0)?query:((t==1)?key:value);
      const f16* WAt = WA + t*36864;
      f16* Yt = QKV + (size_t)t*8388608;
      {
        int ci0 = (ltid & 31)*2;
        int row = (ltid >> 5) & 3;
        int dh  = (ltid >> 7) * 32;
        int gr  = l0 - 1 + row;
        bool valid = (unsigned)gr < 256u;
        int grc = valid ? gr : 0;
        const f32x4* s0 = (const f32x4*)(X + (((size_t)(b*64+ci0  )*256 + grc)*64 + dh));
        const f32x4* s1 = (const f32x4*)(X + (((size_t)(b*64+ci0+1)*256 + grc)*64 + dh));
#pragma unroll
        for (int q=0;q<8;++q) {
          f32x4 f0 = valid ? s0[q] : fz4();
          f32x4 f1 = valid ? s1[q] : fz4();
#pragma unroll
          for (int e=0;e<4;++e) {
            int d = dh + q*4 + e;
            int idx = ((row*64 + d)*64 + ci0) ^ ((d&7)<<3);   // Xs[row][d][ci]
            unsigned int pk = (unsigned int)__builtin_bit_cast(unsigned short,(f16)f0[e])
                            | ((unsigned int)__builtin_bit_cast(unsigned short,(f16)f1[e]) << 16);
            *(unsigned int*)&hs[idx] = pk;
          }
        }
      }
      __syncthreads();
      f32x4 acc[4][2];
#pragma unroll
      for (int mt=0;mt<4;++mt){ acc[mt][0]=fz4(); acc[mt][1]=fz4(); }
      for (int kstep=0; kstep<18; ++kstep) {
        int sp = kstep >> 1;
        int sp3 = sp/3;
        int dl = sp3 - 1;
        int dd = (sp - sp3*3) - 1;
        int cib = (kstep & 1)*32;
        const f16* wp = WAt + kstep*2048 + lr*32 + kh*8;
        f16x8 a0 = *(const f16x8*)(wp);
        f16x8 a1 = *(const f16x8*)(wp + 512);
        f16x8 a2 = *(const f16x8*)(wp + 1024);
        f16x8 a3 = *(const f16x8*)(wp + 1536);
        f16x8 bb[2];
#pragma unroll
        for (int nt=0;nt<2;++nt) {
          int n = wvl*32 + nt*16 + lr;
          int lloc = n >> 6, d = n & 63;
          int dp = d + dd;
          bool v = (unsigned)dp < 64u;
          int dpc = dp & 63;
          int rowi = lloc + dl + 1;
          int idx = ((rowi*64 + dpc)*64 + cib + kh*8) ^ ((dpc&7)<<3);
          f16x8 tt = *(const f16x8*)&hs[idx];
          if (!v) tt = hz8();
          bb[nt] = tt;
        }
#pragma unroll
        for (int nt=0;nt<2;++nt) {
          acc[0][nt] = MFMA(a0, bb[nt], acc[0][nt]);
          acc[1][nt] = MFMA(a1, bb[nt], acc[1][nt]);
          acc[2][nt] = MFMA(a2, bb[nt], acc[2][nt]);
          acc[3][nt] = MFMA(a3, bb[nt], acc[3][nt]);
        }
      }
#pragma unroll
      for (int mt=0;mt<4;++mt)
#pragma unroll
      for (int nt=0;nt<2;++nt)
#pragma unroll
      for (int r=0;r<4;++r) {
        int co = mt*16 + kh*4 + r;
        int n = wvl*32 + nt*16 + lr;
        int lrow = l0 + (n>>6), d = n & 63;
        Yt[((size_t)(b*64+co)*256 + lrow)*64 + d] = (f16)acc[mt][nt][r];
      }
      __syncthreads();
    }
  }
  grid_barrier(bar, nblk);

  // phase 2: flash attention; instances = 512/nblk per block, 8 waves x 32 q-rows.
  {
    int inst = 512 / (int)nblk;
    for (int k2 = 0; k2 < inst; ++k2) {
      int idx = bid + k2*(int)nblk;
      int bc = (idx & 7)*64 + (idx >> 3);   // batch = bid&7 = producer XCD
      const f16* Qs = QKV + (size_t)bc*16384;
      const f16* Ks = QKV +  8388608 + (size_t)bc*16384;
      const f16* Vs = QKV + 16777216 + (size_t)bc*16384;
      __syncthreads();
      {
        int m  = tid & 63;
        int dg = (tid >> 6) * 8;
#pragma unroll
        for (int pass=0; pass<4; ++pass) {
          int mm = m + pass*64;
          f16x8 v0 = *(const f16x8*)(Vs + mm*64 + dg);
#pragma unroll
          for (int e=0;e<8;++e){ int d=dg+e; smem[(d*256+mm) ^ ((d&7)<<3)] = v0[e]; }
        }
      }
      int l0g = wvg*32;
      f16x8 qf[2][2];
#pragma unroll
      for (int lt=0;lt<2;++lt)
#pragma unroll
      for (int ks=0;ks<2;++ks)
        qf[lt][ks] = *(const f16x8*)(Qs + (l0g + lt*16 + lr)*64 + ks*32 + kh*8);
      f32x4 O[2][4];
      float rm[2][4], rl[2][4];
#pragma unroll
      for (int lt=0;lt<2;++lt)
#pragma unroll
      for (int x=0;x<4;++x) { O[lt][x]=fz4(); rm[lt][x]=-1e30f; rl[lt][x]=0.f; }
      __syncthreads();
      f16* P = &smem[16384 + wvg*2048];
      for (int it=0; it<4; ++it) {
        int m0 = it*64;
        f32x4 s[2][4];
#pragma unroll
        for (int lt=0;lt<2;++lt)
#pragma unroll
        for (int mt=0;mt<4;++mt) s[lt][mt]=fz4();
#pragma unroll
        for (int ks=0;ks<2;++ks) {
          f16x8 kf[4];
#pragma unroll
          for (int mt=0;mt<4;++mt)
            kf[mt] = *(const f16x8*)(Ks + (m0 + mt*16 + lr)*64 + ks*32 + kh*8);
#pragma unroll
          for (int lt=0;lt<2;++lt)
#pragma unroll
          for (int mt=0;mt<4;++mt)
            s[lt][mt] = MFMA(qf[lt][ks], kf[mt], s[lt][mt]);
        }
#pragma unroll
        for (int lt=0;lt<2;++lt)
#pragma unroll
        for (int r=0;r<4;++r) {
          float tm = fmaxf(fmaxf(s[lt][0][r], s[lt][1][r]), fmaxf(s[lt][2][r], s[lt][3][r]));
#pragma unroll
          for (int off=1; off<16; off<<=1) tm = fmaxf(tm, __shfl_xor(tm, off));
          float mo = rm[lt][r];
          float mn = fmaxf(mo, tm);
          rm[lt][r] = mn;
          float corr = __expf(mo - mn);
          float sum = 0.f;
#pragma unroll
          for (int mt=0;mt<4;++mt) { float p = __expf(s[lt][mt][r] - mn); s[lt][mt][r] = p; sum += p; }
#pragma unroll
          for (int off=1; off<16; off<<=1) sum += __shfl_xor(sum, off);
          rl[lt][r] = rl[lt][r]*corr + sum;
#pragma unroll
          for (int dt=0;dt<4;++dt) O[lt][dt][r] *= corr;
        }
#pragma unroll
        for (int lt=0;lt<2;++lt)
#pragma unroll
        for (int mt=0;mt<4;++mt)
#pragma unroll
        for (int r=0;r<4;++r) {
          int row = lt*16 + kh*4 + r;
          P[(row*64 + mt*16 + lr) ^ ((row&7)<<3)] = (f16)s[lt][mt][r];
        }
#pragma unroll
        for (int ks=0;ks<2;++ks) {
          f16x8 pa[2], vb[4];
#pragma unroll
          for (int lt=0;lt<2;++lt) {
            int row = lt*16 + lr;
            pa[lt] = *(const f16x8*)&P[(row*64 + ks*32 + kh*8) ^ ((row&7)<<3)];
          }
#pragma unroll
          for (int dt=0;dt<4;++dt) {
            int d = dt*16 + lr;
            vb[dt] = *(const f16x8*)&smem[(d*256 + m0 + ks*32 + kh*8) ^ ((d&7)<<3)];
          }
#pragma unroll
          for (int lt=0;lt<2;++lt)
#pragma unroll
          for (int dt=0;dt<4;++dt)
            O[lt][dt] = MFMA(pa[lt], vb[dt], O[lt][dt]);
        }
      }
#pragma unroll
      for (int lt=0;lt<2;++lt)
#pragma unroll
      for (int r=0;r<4;++r) {
        float inv = 1.f / rl[lt][r];
        int row = l0g + lt*16 + kh*4 + r;
#pragma unroll
        for (int dt=0;dt<4;++dt)
          AO[(size_t)bc*16384 + row*64 + dt*16 + lr] = (f16)(O[lt][dt][r]*inv);
      }
    }
  }
  grid_barrier(bar, nblk);

  // phase 3: 1x1 conv + bias + residual + LN; tiles = 1024, iters = 1024/(2*nblk).
  {
    int iters = 1024 / (2*(int)nblk);
    for (int iter = 0; iter < iters; ++iter) {
      int w  = bid + (iter*2 + half)*(int)nblk;
      int b  = w & 7;
      int p0 = (w >> 3) * 128;
      {
        int ci = ltid & 63;
        int pg = ltid >> 6;
        const f16* src = AO + (size_t)(b*64+ci)*16384 + p0 + pg*32;
        f16x8 v[4];
#pragma unroll
        for (int q=0;q<4;++q) v[q] = *(const f16x8*)(src + q*8);
#pragma unroll
        for (int q=0;q<4;++q)
#pragma unroll
        for (int e=0;e<8;++e) {
          int p = pg*32 + q*8 + e;
          hs[(p*64 + ci) ^ ((p&7)<<3)] = v[q][e];
        }
        int co  = ltid >> 2;
        int cig = (ltid & 3) * 16;
        const f32x4* wsrc = (const f32x4*)(Wo + co*64 + cig);
        f32x4 w0 = wsrc[0], w1 = wsrc[1], w2 = wsrc[2], w3 = wsrc[3];
        f16x8 g0, g1;
#pragma unroll
        for (int e=0;e<4;++e) { g0[e]=(f16)w0[e]; g0[4+e]=(f16)w1[e]; g1[e]=(f16)w2[e]; g1[4+e]=(f16)w3[e]; }
        *(f16x8*)&hs[8192 + ((co*64 + cig    ) ^ ((co&7)<<3))] = g0;
        *(f16x8*)&hs[8192 + ((co*64 + cig + 8) ^ ((co&7)<<3))] = g1;
      }
      __syncthreads();
      int n0 = wvl*32;
      f32x4 acc[4][2];
#pragma unroll
      for (int mt=0;mt<4;++mt){ acc[mt][0]=fz4(); acc[mt][1]=fz4(); }
#pragma unroll
      for (int ks=0;ks<2;++ks) {
        f16x8 a[4], bb[2];
#pragma unroll
        for (int mt=0;mt<4;++mt)
          a[mt] = *(const f16x8*)&hs[8192 + (((mt*16+lr)*64 + ks*32 + kh*8) ^ ((lr&7)<<3))];
#pragma unroll
        for (int nt=0;nt<2;++nt) {
          int p = n0 + nt*16 + lr;
          bb[nt] = *(const f16x8*)&hs[(p*64 + ks*32 + kh*8) ^ ((p&7)<<3)];
        }
#pragma unroll
        for (int mt=0;mt<4;++mt)
#pragma unroll
        for (int nt=0;nt<2;++nt)
          acc[mt][nt] = MFMA(a[mt], bb[nt], acc[mt][nt]);
      }
      float vals[4][2][4];
      float sum0=0.f, sq0=0.f, sum1=0.f, sq1=0.f;
#pragma unroll
      for (int mt=0;mt<4;++mt)
#pragma unroll
      for (int nt=0;nt<2;++nt)
#pragma unroll
      for (int r=0;r<4;++r) {
        int co = mt*16 + kh*4 + r;
        int p  = p0 + n0 + nt*16 + lr;
        float v = acc[mt][nt][r] + bo[co] + query[(size_t)(b*64+co)*16384 + p];
        vals[mt][nt][r] = v;
        if (nt==0) { sum0 += v; sq0 += v*v; } else { sum1 += v; sq1 += v*v; }
      }
#pragma unroll
      for (int off=16; off<64; off<<=1) {
        sum0 += __shfl_xor(sum0, off); sq0 += __shfl_xor(sq0, off);
        sum1 += __shfl_xor(sum1, off); sq1 += __shfl_xor(sq1, off);
      }
      float mu0 = sum0*(1.f/64.f), var0 = sq0*(1.f/64.f) - mu0*mu0, rs0 = rsqrtf(var0 + 1e-5f);
      float mu1 = sum1*(1.f/64.f), var1 = sq1*(1.f/64.f) - mu1*mu1, rs1 = rsqrtf(var1 + 1e-5f);
#pragma unroll
      for (int mt=0;mt<4;++mt)
#pragma unroll
      for (int nt=0;nt<2;++nt)
#pragma unroll
      for (int r=0;r<4;++r) {
        int co = mt*16 + kh*4 + r;
        int p  = p0 + n0 + nt*16 + lr;
        float mu = nt ? mu1 : mu0;
        float rs = nt ? rs1 : rs0;
        out[(size_t)(b*64+co)*16384 + p] = (vals[mt][nt][r] - mu)*rs*gamma[co] + beta[co];
      }
      __syncthreads();
    }
  }
}

extern "C" void kernel_launch(void* const* d_in, const int* in_sizes, int n_in,
                              void* d_out, int out_size, void* d_ws, size_t ws_size,
                              hipStream_t stream)
{
  const float* query = (const float*)d_in[0];
  const float* key   = (const float*)d_in[1];
  const float* value = (const float*)d_in[2];
  const float* Wq = (const float*)d_in[3];
  const float* Wk = (const float*)d_in[4];
  const float* Wv = (const float*)d_in[5];
  const float* Wo = (const float*)d_in[6];
  const float* bo = (const float*)d_in[7];
  const float* gamma = (const float*)d_in[8];
  const float* beta  = (const float*)d_in[9];
  char* ws = (char*)d_ws;
  // ws: QKV [0,48MiB) | AO [48,64MiB) — exactly 64 MiB.
  // d_out head: WA (216 KiB) phase-0 scratch; barrier words at +1 MiB
  // (zeroed each call); phase 3 overwrites all of d_out last.
  f16*      QKV  = (f16*)ws;
  f16*      AO   = (f16*)(ws + (size_t)50331648);
  f16*      WA   = (f16*)d_out;
  float*    outp = (float*)d_out;
  unsigned* bar  = (unsigned*)((char*)d_out + (size_t)(1<<20));

  // Safe occupancy upgrade: run 2 blocks/CU (512 blocks) ONLY if the occupancy
  // model confirms co-residency (barrier requires all blocks resident).
  // Deterministic per device -> same work every call (graph-capture safe).
  int maxb = 0;
  hipOccupancyMaxActiveBlocksPerMultiprocessor(&maxb, mega, 512, 0);
  unsigned nblk = (maxb >= 2) ? 512u : 256u;

  hipMemsetAsync(bar, 0, 64, stream);
  mega<<<dim3(nblk), dim3(512), 0, stream>>>(
      query, key, value, Wq, Wk, Wv, Wo, bo, gamma, beta,
      QKV, AO, WA, outp, bar, nblk);
}

// Round 16
// 294.193 us; speedup vs baseline: 1.7256x; 1.1384x over previous
//
#include <hip/hip_runtime.h>

// Problem constants: B=8, C=64, L=256, D=64, H=4, HD=16
typedef _Float16 f16;
typedef f16   f16x8 __attribute__((ext_vector_type(8)));
typedef float f32x4 __attribute__((ext_vector_type(4)));

#define MFMA(a,b,c) __builtin_amdgcn_mfma_f32_16x16x32_f16(a,b,c,0,0,0)

__device__ __forceinline__ f32x4 fz4(){ f32x4 z; z[0]=0.f; z[1]=0.f; z[2]=0.f; z[3]=0.f; return z; }
__device__ __forceinline__ f16x8 hz8(){ f16x8 z;
#pragma unroll
  for(int i=0;i<8;++i) z[i]=(f16)0.f;
  return z; }

#define NBLK 256u

// Device-scope sense-reversing grid barrier (r9/r10-proven).
__device__ __forceinline__ void grid_barrier(unsigned* bar) {
  __syncthreads();
  if (threadIdx.x == 0) {
    __threadfence();
    unsigned gen  = atomicAdd(&bar[1], 0u);
    unsigned prev = atomicAdd(&bar[0], 1u);
    if (prev == NBLK - 1u) {
      atomicExch(&bar[0], 0u);
      __threadfence();
      atomicAdd(&bar[1], 1u);
    } else {
      while (atomicAdd(&bar[1], 0u) == gen) __builtin_amdgcn_s_sleep(2);
    }
    __threadfence();
  }
  __syncthreads();
}

// ONE kernel, 256 blocks x 512 threads (r10 launch config: 2 waves/SIMD,
// VGPR cap 256 -> no spills). Phases: prep -> conv -> attn -> proj+LN.
// r16 delta vs r10 (conv phase only): double-buffered register-staged tiles
// (global loads of tile i+1 issued before compute of tile i) + 1-deep weight
// prefetch in the kstep loop. LDS 128 KiB (2 conv bufs per half-block).
__global__ __launch_bounds__(512, 2) void mega(
    const float* __restrict__ query, const float* __restrict__ key,
    const float* __restrict__ value,
    const float* __restrict__ Wq, const float* __restrict__ Wk,
    const float* __restrict__ Wv, const float* __restrict__ Wo,
    const float* __restrict__ bo, const float* __restrict__ gamma,
    const float* __restrict__ beta,
    f16* __restrict__ QKV, f16* __restrict__ AO,
    f16* WA, float* out, unsigned* bar)
{
  __shared__ f16 smem[65536];   // 128 KiB: conv dbuf; attn/proj use first 64 KiB
  const int tid  = threadIdx.x;
  const int bid  = blockIdx.x;
  const int half = tid >> 8;
  const int ltid = tid & 255;
  const int lane = tid & 63;
  const int wvg  = tid >> 6;
  const int wvl  = (ltid >> 6);
  const int lr   = lane & 15, kh = lane >> 4;
  f16* hs = smem + half*16384;

  // phase 0: weight prepack (Q weights pre-scaled 0.25 = 1/sqrt(HD))
  // WA[tensor][kstep(18)][co(64)][kq(4)][j(8)], k=kstep*32+kq*8+j=(ky*3+kx)*64+ci
  {
    int gid = bid*512 + tid;
    if (gid < 110592) {
      int t = gid / 36864, r = gid % 36864;
      const float* W = (t==0)?Wq:((t==1)?Wk:Wv);
      float sc = (t==0) ? 0.25f : 1.0f;
      int kstep = r >> 11, rem = r & 2047;
      int co = rem >> 5, rem2 = rem & 31;
      int kq = rem2 >> 3, j = rem2 & 7;
      int k = kstep*32 + kq*8 + j;
      int sp = k >> 6, ci = k & 63;
      int ky = sp/3, kx = sp - ky*3;
      WA[gid] = (f16)(W[((co*64+ci)*3+ky)*3+kx]*sc);
    }
  }
  grid_barrier(bar);

  // ===== phase 1: conv3x3, half-block per tile, 6 iters, double-buffered =====
  {
    f16* bufA = smem + half*16384;            // [0,32KiB) region of this half
    f16* bufB = smem + 32768 + half*16384;    // second buffer
    const int ci0 = (ltid & 31)*2;
    const int row = (ltid >> 5) & 3;
    const int dh  = (ltid >> 7) * 32;

    f32x4 r0[8], r1[8];
    int ct=0, cl0=0, cb=0;

    auto conv_load = [&](int iter, int& t_o, int& l0_o, int& b_o) {
      int w    = bid + (iter*2 + half)*256;
      int b    = w & 7;
      int rest = w >> 3;
      int t    = rest >> 7;
      int l0   = (rest & 127) * 2;
      const float* X = (t==0)?query:((t==1)?key:value);
      int gr  = l0 - 1 + row;
      bool valid = (unsigned)gr < 256u;
      int grc = valid ? gr : 0;
      const f32x4* s0 = (const f32x4*)(X + (((size_t)(b*64+ci0  )*256 + grc)*64 + dh));
      const f32x4* s1 = (const f32x4*)(X + (((size_t)(b*64+ci0+1)*256 + grc)*64 + dh));
#pragma unroll
      for (int q=0;q<8;++q) {
        r0[q] = valid ? s0[q] : fz4();
        r1[q] = valid ? s1[q] : fz4();
      }
      t_o = t; l0_o = l0; b_o = b;
    };

    auto conv_write = [&](f16* buf) {
#pragma unroll
      for (int q=0;q<8;++q)
#pragma unroll
      for (int e=0;e<4;++e) {
        int d = dh + q*4 + e;
        int idx = ((row*64 + d)*64 + ci0) ^ ((d&7)<<3);   // Xs[row][d][ci]
        unsigned int pk = (unsigned int)__builtin_bit_cast(unsigned short,(f16)r0[q][e])
                        | ((unsigned int)__builtin_bit_cast(unsigned short,(f16)r1[q][e]) << 16);
        *(unsigned int*)&buf[idx] = pk;
      }
    };

    auto conv_compute = [&](const f16* buf, int t, int l0, int b) {
      const f16* WAt = WA + t*36864;
      f16* Yt = QKV + (size_t)t*8388608;
      f32x4 acc[4][2];
#pragma unroll
      for (int mt=0;mt<4;++mt){ acc[mt][0]=fz4(); acc[mt][1]=fz4(); }
      const f16* wbase = WAt + lr*32 + kh*8;
      f16x8 a0 = *(const f16x8*)(wbase);
      f16x8 a1 = *(const f16x8*)(wbase + 512);
      f16x8 a2 = *(const f16x8*)(wbase + 1024);
      f16x8 a3 = *(const f16x8*)(wbase + 1536);
      for (int kstep=0; kstep<18; ++kstep) {
        f16x8 n0, n1, n2, n3;
        if (kstep < 17) {               // 1-deep weight prefetch (breaks chain)
          const f16* wp = wbase + (kstep+1)*2048;
          n0 = *(const f16x8*)(wp);
          n1 = *(const f16x8*)(wp + 512);
          n2 = *(const f16x8*)(wp + 1024);
          n3 = *(const f16x8*)(wp + 1536);
        }
        int sp = kstep >> 1;
        int sp3 = sp/3;
        int dl = sp3 - 1;
        int dd = (sp - sp3*3) - 1;
        int cib = (kstep & 1)*32;
        f16x8 bb[2];
#pragma unroll
        for (int nt=0;nt<2;++nt) {
          int n = wvl*32 + nt*16 + lr;
          int lloc = n >> 6, d = n & 63;
          int dp = d + dd;
          bool v = (unsigned)dp < 64u;
          int dpc = dp & 63;
          int rowi = lloc + dl + 1;
          int idx = ((rowi*64 + dpc)*64 + cib + kh*8) ^ ((dpc&7)<<3);
          f16x8 tt = *(const f16x8*)&buf[idx];
          if (!v) tt = hz8();
          bb[nt] = tt;
        }
#pragma unroll
        for (int nt=0;nt<2;++nt) {
          acc[0][nt] = MFMA(a0, bb[nt], acc[0][nt]);
          acc[1][nt] = MFMA(a1, bb[nt], acc[1][nt]);
          acc[2][nt] = MFMA(a2, bb[nt], acc[2][nt]);
          acc[3][nt] = MFMA(a3, bb[nt], acc[3][nt]);
        }
        a0 = n0; a1 = n1; a2 = n2; a3 = n3;
      }
#pragma unroll
      for (int mt=0;mt<4;++mt)
#pragma unroll
      for (int nt=0;nt<2;++nt)
#pragma unroll
      for (int r=0;r<4;++r) {
        int co = mt*16 + kh*4 + r;
        int n = wvl*32 + nt*16 + lr;
        int lrow = l0 + (n>>6), d = n & 63;
        Yt[((size_t)(b*64+co)*256 + lrow)*64 + d] = (f16)acc[mt][nt][r];
      }
    };

    // prologue: stage tile 0
    conv_load(0, ct, cl0, cb);
    conv_write(bufA);
    __syncthreads();
    for (int iter = 0; iter < 6; ++iter) {
      int nt_=0, nl0=0, nb=0;
      if (iter < 5) conv_load(iter+1, nt_, nl0, nb);   // issue global loads early
      conv_compute((iter & 1) ? bufB : bufA, ct, cl0, cb);
      if (iter < 5) {
        __syncthreads();                                // all reads of nxt (iter-1) done
        conv_write((iter & 1) ? bufA : bufB);
        __syncthreads();                                // writes visible before compute
        ct = nt_; cl0 = nl0; cb = nb;
      }
    }
  }
  grid_barrier(bar);

  // phase 2: flash attention (r10-verbatim), 2 instances, 8 waves x 32 q-rows
  for (int k2 = 0; k2 < 2; ++k2) {
    int idx = bid + k2*256;
    int bc = (idx & 7)*64 + (idx >> 3);
    const f16* Qs = QKV + (size_t)bc*16384;
    const f16* Ks = QKV +  8388608 + (size_t)bc*16384;
    const f16* Vs = QKV + 16777216 + (size_t)bc*16384;
    __syncthreads();
    {
      int m  = tid & 63;
      int dg = (tid >> 6) * 8;
#pragma unroll
      for (int pass=0; pass<4; ++pass) {
        int mm = m + pass*64;
        f16x8 v0 = *(const f16x8*)(Vs + mm*64 + dg);
#pragma unroll
        for (int e=0;e<8;++e){ int d=dg+e; smem[(d*256+mm) ^ ((d&7)<<3)] = v0[e]; }
      }
    }
    int l0g = wvg*32;
    f16x8 qf[2][2];
#pragma unroll
    for (int lt=0;lt<2;++lt)
#pragma unroll
    for (int ks=0;ks<2;++ks)
      qf[lt][ks] = *(const f16x8*)(Qs + (l0g + lt*16 + lr)*64 + ks*32 + kh*8);
    f32x4 O[2][4];
    float rm[2][4], rl[2][4];
#pragma unroll
    for (int lt=0;lt<2;++lt)
#pragma unroll
    for (int x=0;x<4;++x) { O[lt][x]=fz4(); rm[lt][x]=-1e30f; rl[lt][x]=0.f; }
    __syncthreads();
    f16* P = &smem[16384 + wvg*2048];
    for (int it=0; it<4; ++it) {
      int m0 = it*64;
      f32x4 s[2][4];
#pragma unroll
      for (int lt=0;lt<2;++lt)
#pragma unroll
      for (int mt=0;mt<4;++mt) s[lt][mt]=fz4();
#pragma unroll
      for (int ks=0;ks<2;++ks) {
        f16x8 kf[4];
#pragma unroll
        for (int mt=0;mt<4;++mt)
          kf[mt] = *(const f16x8*)(Ks + (m0 + mt*16 + lr)*64 + ks*32 + kh*8);
#pragma unroll
        for (int lt=0;lt<2;++lt)
#pragma unroll
        for (int mt=0;mt<4;++mt)
          s[lt][mt] = MFMA(qf[lt][ks], kf[mt], s[lt][mt]);
      }
#pragma unroll
      for (int lt=0;lt<2;++lt)
#pragma unroll
      for (int r=0;r<4;++r) {
        float tm = fmaxf(fmaxf(s[lt][0][r], s[lt][1][r]), fmaxf(s[lt][2][r], s[lt][3][r]));
#pragma unroll
        for (int off=1; off<16; off<<=1) tm = fmaxf(tm, __shfl_xor(tm, off));
        float mo = rm[lt][r];
        float mn = fmaxf(mo, tm);
        rm[lt][r] = mn;
        float corr = __expf(mo - mn);
        float sum = 0.f;
#pragma unroll
        for (int mt=0;mt<4;++mt) { float p = __expf(s[lt][mt][r] - mn); s[lt][mt][r] = p; sum += p; }
#pragma unroll
        for (int off=1; off<16; off<<=1) sum += __shfl_xor(sum, off);
        rl[lt][r] = rl[lt][r]*corr + sum;
#pragma unroll
        for (int dt=0;dt<4;++dt) O[lt][dt][r] *= corr;
      }
#pragma unroll
      for (int lt=0;lt<2;++lt)
#pragma unroll
      for (int mt=0;mt<4;++mt)
#pragma unroll
      for (int r=0;r<4;++r) {
        int row = lt*16 + kh*4 + r;
        P[(row*64 + mt*16 + lr) ^ ((row&7)<<3)] = (f16)s[lt][mt][r];
      }
#pragma unroll
      for (int ks=0;ks<2;++ks) {
        f16x8 pa[2], vb[4];
#pragma unroll
        for (int lt=0;lt<2;++lt) {
          int row = lt*16 + lr;
          pa[lt] = *(const f16x8*)&P[(row*64 + ks*32 + kh*8) ^ ((row&7)<<3)];
        }
#pragma unroll
        for (int dt=0;dt<4;++dt) {
          int d = dt*16 + lr;
          vb[dt] = *(const f16x8*)&smem[(d*256 + m0 + ks*32 + kh*8) ^ ((d&7)<<3)];
        }
#pragma unroll
        for (int lt=0;lt<2;++lt)
#pragma unroll
        for (int dt=0;dt<4;++dt)
          O[lt][dt] = MFMA(pa[lt], vb[dt], O[lt][dt]);
      }
    }
#pragma unroll
    for (int lt=0;lt<2;++lt)
#pragma unroll
    for (int r=0;r<4;++r) {
      float inv = 1.f / rl[lt][r];
      int row = l0g + lt*16 + kh*4 + r;
#pragma unroll
      for (int dt=0;dt<4;++dt)
        AO[(size_t)bc*16384 + row*64 + dt*16 + lr] = (f16)(O[lt][dt][r]*inv);
    }
  }
  grid_barrier(bar);

  // phase 3: 1x1 conv + bias + residual + LN (r10-verbatim)
  for (int iter = 0; iter < 2; ++iter) {
    int w  = bid + (iter*2 + half)*256;
    int b  = w & 7;
    int p0 = (w >> 3) * 128;
    {
      int ci = ltid & 63;
      int pg = ltid >> 6;
      const f16* src = AO + (size_t)(b*64+ci)*16384 + p0 + pg*32;
      f16x8 v[4];
#pragma unroll
      for (int q=0;q<4;++q) v[q] = *(const f16x8*)(src + q*8);
#pragma unroll
      for (int q=0;q<4;++q)
#pragma unroll
      for (int e=0;e<8;++e) {
        int p = pg*32 + q*8 + e;
        hs[(p*64 + ci) ^ ((p&7)<<3)] = v[q][e];
      }
      int co  = ltid >> 2;
      int cig = (ltid & 3) * 16;
      const f32x4* wsrc = (const f32x4*)(Wo + co*64 + cig);
      f32x4 w0 = wsrc[0], w1 = wsrc[1], w2 = wsrc[2], w3 = wsrc[3];
      f16x8 g0, g1;
#pragma unroll
      for (int e=0;e<4;++e) { g0[e]=(f16)w0[e]; g0[4+e]=(f16)w1[e]; g1[e]=(f16)w2[e]; g1[4+e]=(f16)w3[e]; }
      *(f16x8*)&hs[8192 + ((co*64 + cig    ) ^ ((co&7)<<3))] = g0;
      *(f16x8*)&hs[8192 + ((co*64 + cig + 8) ^ ((co&7)<<3))] = g1;
    }
    __syncthreads();
    int n0 = wvl*32;
    f32x4 acc[4][2];
#pragma unroll
    for (int mt=0;mt<4;++mt){ acc[mt][0]=fz4(); acc[mt][1]=fz4(); }
#pragma unroll
    for (int ks=0;ks<2;++ks) {
      f16x8 a[4], bb[2];
#pragma unroll
      for (int mt=0;mt<4;++mt)
        a[mt] = *(const f16x8*)&hs[8192 + (((mt*16+lr)*64 + ks*32 + kh*8) ^ ((lr&7)<<3))];
#pragma unroll
      for (int nt=0;nt<2;++nt) {
        int p = n0 + nt*16 + lr;
        bb[nt] = *(const f16x8*)&hs[(p*64 + ks*32 + kh*8) ^ ((p&7)<<3)];
      }
#pragma unroll
      for (int mt=0;mt<4;++mt)
#pragma unroll
      for (int nt=0;nt<2;++nt)
        acc[mt][nt] = MFMA(a[mt], bb[nt], acc[mt][nt]);
    }
    float vals[4][2][4];
    float sum0=0.f, sq0=0.f, sum1=0.f, sq1=0.f;
#pragma unroll
    for (int mt=0;mt<4;++mt)
#pragma unroll
    for (int nt=0;nt<2;++nt)
#pragma unroll
    for (int r=0;r<4;++r) {
      int co = mt*16 + kh*4 + r;
      int p  = p0 + n0 + nt*16 + lr;
      float v = acc[mt][nt][r] + bo[co] + query[(size_t)(b*64+co)*16384 + p];
      vals[mt][nt][r] = v;
      if (nt==0) { sum0 += v; sq0 += v*v; } else { sum1 += v; sq1 += v*v; }
    }
#pragma unroll
    for (int off=16; off<64; off<<=1) {
      sum0 += __shfl_xor(sum0, off); sq0 += __shfl_xor(sq0, off);
      sum1 += __shfl_xor(sum1, off); sq1 += __shfl_xor(sq1, off);
    }
    float mu0 = sum0*(1.f/64.f), var0 = sq0*(1.f/64.f) - mu0*mu0, rs0 = rsqrtf(var0 + 1e-5f);
    float mu1 = sum1*(1.f/64.f), var1 = sq1*(1.f/64.f) - mu1*mu1, rs1 = rsqrtf(var1 + 1e-5f);
#pragma unroll
    for (int mt=0;mt<4;++mt)
#pragma unroll
    for (int nt=0;nt<2;++nt)
#pragma unroll
    for (int r=0;r<4;++r) {
      int co = mt*16 + kh*4 + r;
      int p  = p0 + n0 + nt*16 + lr;
      float mu = nt ? mu1 : mu0;
      float rs = nt ? rs1 : rs0;
      out[(size_t)(b*64+co)*16384 + p] = (vals[mt][nt][r] - mu)*rs*gamma[co] + beta[co];
    }
    __syncthreads();
  }
}

extern "C" void kernel_launch(void* const* d_in, const int* in_sizes, int n_in,
                              void* d_out, int out_size, void* d_ws, size_t ws_size,
                              hipStream_t stream)
{
  const float* query = (const float*)d_in[0];
  const float* key   = (const float*)d_in[1];
  const float* value = (const float*)d_in[2];
  const float* Wq = (const float*)d_in[3];
  const float* Wk = (const float*)d_in[4];
  const float* Wv = (const float*)d_in[5];
  const float* Wo = (const float*)d_in[6];
  const float* bo = (const float*)d_in[7];
  const float* gamma = (const float*)d_in[8];
  const float* beta  = (const float*)d_in[9];
  char* ws = (char*)d_ws;
  // ws: QKV [0,48MiB) | AO [48,64MiB) — exactly 64 MiB.
  // d_out head: WA (216 KiB) phase-0 scratch; barrier words at +1 MiB
  // (zeroed each call); phase 3 overwrites all of d_out last.
  f16*      QKV  = (f16*)ws;
  f16*      AO   = (f16*)(ws + (size_t)50331648);
  f16*      WA   = (f16*)d_out;
  float*    outp = (float*)d_out;
  unsigned* bar  = (unsigned*)((char*)d_out + (size_t)(1<<20));

  hipMemsetAsync(bar, 0, 64, stream);
  mega<<<dim3(NBLK), dim3(512), 0, stream>>>(
      query, key, value, Wq, Wk, Wv, Wo, bo, gamma, beta,
      QKV, AO, WA, outp, bar);
}

// Round 17
// 200.600 us; speedup vs baseline: 2.5306x; 1.4666x over previous
//
#include <hip/hip_runtime.h>

// Problem constants: B=8, C=64, L=256, D=64, H=4, HD=16
typedef _Float16 f16;
typedef f16   f16x8 __attribute__((ext_vector_type(8)));
typedef float f32x4 __attribute__((ext_vector_type(4)));

#define MFMA(a,b,c) __builtin_amdgcn_mfma_f32_16x16x32_f16(a,b,c,0,0,0)

__device__ __forceinline__ f32x4 fz4(){ f32x4 z; z[0]=0.f; z[1]=0.f; z[2]=0.f; z[3]=0.f; return z; }
__device__ __forceinline__ f16x8 hz8(){ f16x8 z;
#pragma unroll
  for(int i=0;i<8;++i) z[i]=(f16)0.f;
  return z; }

#define NBLK 256u

// Two-level line-padded grid barrier (r17). The r9/r10 single-counter barrier
// put arrivals (bar[0]) and the 255-spinner RMW-poll (bar[1]) on ONE cache
// line -> cross-XCD line ping-pong per op (~50-75us/barrier suspected).
// Here: 8 group counters at bar[g*32] (128B apart; bid&7 matches XCD
// round-robin so each group line stays XCD-local), 32 local RMWs each in
// parallel; last-of-group does 1 RMW on bar[256]; 8th bumps gen bar[288].
// Ordering preserved from r9: gen read BEFORE arrival; counters reset BEFORE
// the gen bump; no lap possible (gen k+1 needs all blocks past gen k).
__device__ __forceinline__ void grid_barrier(unsigned* bar) {
  __syncthreads();
  if (threadIdx.x == 0) {
    __threadfence();
    unsigned gen0 = atomicAdd(&bar[288], 0u);
    int g = blockIdx.x & 7;
    unsigned p = atomicAdd(&bar[g*32], 1u);
    if (p == 31u) {                       // last of my 32-block group
      atomicExch(&bar[g*32], 0u);
      unsigned q = atomicAdd(&bar[256], 1u);
      if (q == 7u) {                      // last group
        atomicExch(&bar[256], 0u);
        __threadfence();
        atomicAdd(&bar[288], 1u);         // release all
      } else {
        while (atomicAdd(&bar[288], 0u) == gen0) __builtin_amdgcn_s_sleep(2);
      }
    } else {
      while (atomicAdd(&bar[288], 0u) == gen0) __builtin_amdgcn_s_sleep(2);
    }
    __threadfence();
  }
  __syncthreads();
}

// ONE kernel, 256 blocks x 512 threads — r10-exact body (238.8us best),
// only the grid barrier implementation changed (single-variable experiment).
__global__ __launch_bounds__(512, 2) void mega(
    const float* __restrict__ query, const float* __restrict__ key,
    const float* __restrict__ value,
    const float* __restrict__ Wq, const float* __restrict__ Wk,
    const float* __restrict__ Wv, const float* __restrict__ Wo,
    const float* __restrict__ bo, const float* __restrict__ gamma,
    const float* __restrict__ beta,
    f16* __restrict__ QKV, f16* __restrict__ AO,
    f16* WA, float* out, unsigned* bar)
{
  __shared__ f16 smem[32768];
  const int tid  = threadIdx.x;
  const int bid  = blockIdx.x;
  const int half = tid >> 8;
  const int ltid = tid & 255;
  const int lane = tid & 63;
  const int wvg  = tid >> 6;
  const int wvl  = (ltid >> 6);
  const int lr   = lane & 15, kh = lane >> 4;
  f16* hs = smem + half*16384;

  // phase 0: weight prepack (Q weights pre-scaled 0.25 = 1/sqrt(HD))
  // WA[tensor][kstep(18)][co(64)][kq(4)][j(8)], k=kstep*32+kq*8+j=(ky*3+kx)*64+ci
  {
    int gid = bid*512 + tid;
    if (gid < 110592) {
      int t = gid / 36864, r = gid % 36864;
      const float* W = (t==0)?Wq:((t==1)?Wk:Wv);
      float sc = (t==0) ? 0.25f : 1.0f;
      int kstep = r >> 11, rem = r & 2047;
      int co = rem >> 5, rem2 = rem & 31;
      int kq = rem2 >> 3, j = rem2 & 7;
      int k = kstep*32 + kq*8 + j;
      int sp = k >> 6, ci = k & 63;
      int ky = sp/3, kx = sp - ky*3;
      WA[gid] = (f16)(W[((co*64+ci)*3+ky)*3+kx]*sc);
    }
  }
  grid_barrier(bar);

  // phase 1: conv3x3, half-block per tile, 6 iters (r10-verbatim)
  for (int iter = 0; iter < 6; ++iter) {
    int w    = bid + (iter*2 + half)*256;
    int b    = w & 7;
    int rest = w >> 3;
    int t    = rest >> 7;
    int l0   = (rest & 127) * 2;
    const float* X = (t==0)?query:((t==1)?key:value);
    const f16* WAt = WA + t*36864;
    f16* Yt = QKV + (size_t)t*8388608;
    {
      int ci0 = (ltid & 31)*2;
      int row = (ltid >> 5) & 3;
      int dh  = (ltid >> 7) * 32;
      int gr  = l0 - 1 + row;
      bool valid = (unsigned)gr < 256u;
      int grc = valid ? gr : 0;
      const f32x4* s0 = (const f32x4*)(X + (((size_t)(b*64+ci0  )*256 + grc)*64 + dh));
      const f32x4* s1 = (const f32x4*)(X + (((size_t)(b*64+ci0+1)*256 + grc)*64 + dh));
#pragma unroll
      for (int q=0;q<8;++q) {
        f32x4 f0 = valid ? s0[q] : fz4();
        f32x4 f1 = valid ? s1[q] : fz4();
#pragma unroll
        for (int e=0;e<4;++e) {
          int d = dh + q*4 + e;
          int idx = ((row*64 + d)*64 + ci0) ^ ((d&7)<<3);
          unsigned int pk = (unsigned int)__builtin_bit_cast(unsigned short,(f16)f0[e])
                          | ((unsigned int)__builtin_bit_cast(unsigned short,(f16)f1[e]) << 16);
          *(unsigned int*)&hs[idx] = pk;
        }
      }
    }
    __syncthreads();
    f32x4 acc[4][2];
#pragma unroll
    for (int mt=0;mt<4;++mt){ acc[mt][0]=fz4(); acc[mt][1]=fz4(); }
    for (int kstep=0; kstep<18; ++kstep) {
      int sp = kstep >> 1;
      int sp3 = sp/3;
      int dl = sp3 - 1;
      int dd = (sp - sp3*3) - 1;
      int cib = (kstep & 1)*32;
      const f16* wp = WAt + kstep*2048 + lr*32 + kh*8;
      f16x8 a0 = *(const f16x8*)(wp);
      f16x8 a1 = *(const f16x8*)(wp + 512);
      f16x8 a2 = *(const f16x8*)(wp + 1024);
      f16x8 a3 = *(const f16x8*)(wp + 1536);
      f16x8 bb[2];
#pragma unroll
      for (int nt=0;nt<2;++nt) {
        int n = wvl*32 + nt*16 + lr;
        int lloc = n >> 6, d = n & 63;
        int dp = d + dd;
        bool v = (unsigned)dp < 64u;
        int dpc = dp & 63;
        int rowi = lloc + dl + 1;
        int idx = ((rowi*64 + dpc)*64 + cib + kh*8) ^ ((dpc&7)<<3);
        f16x8 tt = *(const f16x8*)&hs[idx];
        if (!v) tt = hz8();
        bb[nt] = tt;
      }
#pragma unroll
      for (int nt=0;nt<2;++nt) {
        acc[0][nt] = MFMA(a0, bb[nt], acc[0][nt]);
        acc[1][nt] = MFMA(a1, bb[nt], acc[1][nt]);
        acc[2][nt] = MFMA(a2, bb[nt], acc[2][nt]);
        acc[3][nt] = MFMA(a3, bb[nt], acc[3][nt]);
      }
    }
#pragma unroll
    for (int mt=0;mt<4;++mt)
#pragma unroll
    for (int nt=0;nt<2;++nt)
#pragma unroll
    for (int r=0;r<4;++r) {
      int co = mt*16 + kh*4 + r;
      int n = wvl*32 + nt*16 + lr;
      int lrow = l0 + (n>>6), d = n & 63;
      Yt[((size_t)(b*64+co)*256 + lrow)*64 + d] = (f16)acc[mt][nt][r];
    }
    __syncthreads();
  }
  grid_barrier(bar);

  // phase 2: flash attention, 2 instances, 8 waves x 32 q-rows (r10-verbatim)
  for (int k2 = 0; k2 < 2; ++k2) {
    int idx = bid + k2*256;
    int bc = (idx & 7)*64 + (idx >> 3);
    const f16* Qs = QKV + (size_t)bc*16384;
    const f16* Ks = QKV +  8388608 + (size_t)bc*16384;
    const f16* Vs = QKV + 16777216 + (size_t)bc*16384;
    __syncthreads();
    {
      int m  = tid & 63;
      int dg = (tid >> 6) * 8;
#pragma unroll
      for (int pass=0; pass<4; ++pass) {
        int mm = m + pass*64;
        f16x8 v0 = *(const f16x8*)(Vs + mm*64 + dg);
#pragma unroll
        for (int e=0;e<8;++e){ int d=dg+e; smem[(d*256+mm) ^ ((d&7)<<3)] = v0[e]; }
      }
    }
    int l0g = wvg*32;
    f16x8 qf[2][2];
#pragma unroll
    for (int lt=0;lt<2;++lt)
#pragma unroll
    for (int ks=0;ks<2;++ks)
      qf[lt][ks] = *(const f16x8*)(Qs + (l0g + lt*16 + lr)*64 + ks*32 + kh*8);
    f32x4 O[2][4];
    float rm[2][4], rl[2][4];
#pragma unroll
    for (int lt=0;lt<2;++lt)
#pragma unroll
    for (int x=0;x<4;++x) { O[lt][x]=fz4(); rm[lt][x]=-1e30f; rl[lt][x]=0.f; }
    __syncthreads();
    f16* P = &smem[16384 + wvg*2048];
    for (int it=0; it<4; ++it) {
      int m0 = it*64;
      f32x4 s[2][4];
#pragma unroll
      for (int lt=0;lt<2;++lt)
#pragma unroll
      for (int mt=0;mt<4;++mt) s[lt][mt]=fz4();
#pragma unroll
      for (int ks=0;ks<2;++ks) {
        f16x8 kf[4];
#pragma unroll
        for (int mt=0;mt<4;++mt)
          kf[mt] = *(const f16x8*)(Ks + (m0 + mt*16 + lr)*64 + ks*32 + kh*8);
#pragma unroll
        for (int lt=0;lt<2;++lt)
#pragma unroll
        for (int mt=0;mt<4;++mt)
          s[lt][mt] = MFMA(qf[lt][ks], kf[mt], s[lt][mt]);
      }
#pragma unroll
      for (int lt=0;lt<2;++lt)
#pragma unroll
      for (int r=0;r<4;++r) {
        float tm = fmaxf(fmaxf(s[lt][0][r], s[lt][1][r]), fmaxf(s[lt][2][r], s[lt][3][r]));
#pragma unroll
        for (int off=1; off<16; off<<=1) tm = fmaxf(tm, __shfl_xor(tm, off));
        float mo = rm[lt][r];
        float mn = fmaxf(mo, tm);
        rm[lt][r] = mn;
        float corr = __expf(mo - mn);
        float sum = 0.f;
#pragma unroll
        for (int mt=0;mt<4;++mt) { float p = __expf(s[lt][mt][r] - mn); s[lt][mt][r] = p; sum += p; }
#pragma unroll
        for (int off=1; off<16; off<<=1) sum += __shfl_xor(sum, off);
        rl[lt][r] = rl[lt][r]*corr + sum;
#pragma unroll
        for (int dt=0;dt<4;++dt) O[lt][dt][r] *= corr;
      }
#pragma unroll
      for (int lt=0;lt<2;++lt)
#pragma unroll
      for (int mt=0;mt<4;++mt)
#pragma unroll
      for (int r=0;r<4;++r) {
        int row = lt*16 + kh*4 + r;
        P[(row*64 + mt*16 + lr) ^ ((row&7)<<3)] = (f16)s[lt][mt][r];
      }
#pragma unroll
      for (int ks=0;ks<2;++ks) {
        f16x8 pa[2], vb[4];
#pragma unroll
        for (int lt=0;lt<2;++lt) {
          int row = lt*16 + lr;
          pa[lt] = *(const f16x8*)&P[(row*64 + ks*32 + kh*8) ^ ((row&7)<<3)];
        }
#pragma unroll
        for (int dt=0;dt<4;++dt) {
          int d = dt*16 + lr;
          vb[dt] = *(const f16x8*)&smem[(d*256 + m0 + ks*32 + kh*8) ^ ((d&7)<<3)];
        }
#pragma unroll
        for (int lt=0;lt<2;++lt)
#pragma unroll
        for (int dt=0;dt<4;++dt)
          O[lt][dt] = MFMA(pa[lt], vb[dt], O[lt][dt]);
      }
    }
#pragma unroll
    for (int lt=0;lt<2;++lt)
#pragma unroll
    for (int r=0;r<4;++r) {
      float inv = 1.f / rl[lt][r];
      int row = l0g + lt*16 + kh*4 + r;
#pragma unroll
      for (int dt=0;dt<4;++dt)
        AO[(size_t)bc*16384 + row*64 + dt*16 + lr] = (f16)(O[lt][dt][r]*inv);
    }
  }
  grid_barrier(bar);

  // phase 3: 1x1 conv + bias + residual + LN (r10-verbatim)
  for (int iter = 0; iter < 2; ++iter) {
    int w  = bid + (iter*2 + half)*256;
    int b  = w & 7;
    int p0 = (w >> 3) * 128;
    {
      int ci = ltid & 63;
      int pg = ltid >> 6;
      const f16* src = AO + (size_t)(b*64+ci)*16384 + p0 + pg*32;
      f16x8 v[4];
#pragma unroll
      for (int q=0;q<4;++q) v[q] = *(const f16x8*)(src + q*8);
#pragma unroll
      for (int q=0;q<4;++q)
#pragma unroll
      for (int e=0;e<8;++e) {
        int p = pg*32 + q*8 + e;
        hs[(p*64 + ci) ^ ((p&7)<<3)] = v[q][e];
      }
      int co  = ltid >> 2;
      int cig = (ltid & 3) * 16;
      const f32x4* wsrc = (const f32x4*)(Wo + co*64 + cig);
      f32x4 w0 = wsrc[0], w1 = wsrc[1], w2 = wsrc[2], w3 = wsrc[3];
      f16x8 g0, g1;
#pragma unroll
      for (int e=0;e<4;++e) { g0[e]=(f16)w0[e]; g0[4+e]=(f16)w1[e]; g1[e]=(f16)w2[e]; g1[4+e]=(f16)w3[e]; }
      *(f16x8*)&hs[8192 + ((co*64 + cig    ) ^ ((co&7)<<3))] = g0;
      *(f16x8*)&hs[8192 + ((co*64 + cig + 8) ^ ((co&7)<<3))] = g1;
    }
    __syncthreads();
    int n0 = wvl*32;
    f32x4 acc[4][2];
#pragma unroll
    for (int mt=0;mt<4;++mt){ acc[mt][0]=fz4(); acc[mt][1]=fz4(); }
#pragma unroll
    for (int ks=0;ks<2;++ks) {
      f16x8 a[4], bb[2];
#pragma unroll
      for (int mt=0;mt<4;++mt)
        a[mt] = *(const f16x8*)&hs[8192 + (((mt*16+lr)*64 + ks*32 + kh*8) ^ ((lr&7)<<3))];
#pragma unroll
      for (int nt=0;nt<2;++nt) {
        int p = n0 + nt*16 + lr;
        bb[nt] = *(const f16x8*)&hs[(p*64 + ks*32 + kh*8) ^ ((p&7)<<3)];
      }
#pragma unroll
      for (int mt=0;mt<4;++mt)
#pragma unroll
      for (int nt=0;nt<2;++nt)
        acc[mt][nt] = MFMA(a[mt], bb[nt], acc[mt][nt]);
    }
    float vals[4][2][4];
    float sum0=0.f, sq0=0.f, sum1=0.f, sq1=0.f;
#pragma unroll
    for (int mt=0;mt<4;++mt)
#pragma unroll
    for (int nt=0;nt<2;++nt)
#pragma unroll
    for (int r=0;r<4;++r) {
      int co = mt*16 + kh*4 + r;
      int p  = p0 + n0 + nt*16 + lr;
      float v = acc[mt][nt][r] + bo[co] + query[(size_t)(b*64+co)*16384 + p];
      vals[mt][nt][r] = v;
      if (nt==0) { sum0 += v; sq0 += v*v; } else { sum1 += v; sq1 += v*v; }
    }
#pragma unroll
    for (int off=16; off<64; off<<=1) {
      sum0 += __shfl_xor(sum0, off); sq0 += __shfl_xor(sq0, off);
      sum1 += __shfl_xor(sum1, off); sq1 += __shfl_xor(sq1, off);
    }
    float mu0 = sum0*(1.f/64.f), var0 = sq0*(1.f/64.f) - mu0*mu0, rs0 = rsqrtf(var0 + 1e-5f);
    float mu1 = sum1*(1.f/64.f), var1 = sq1*(1.f/64.f) - mu1*mu1, rs1 = rsqrtf(var1 + 1e-5f);
#pragma unroll
    for (int mt=0;mt<4;++mt)
#pragma unroll
    for (int nt=0;nt<2;++nt)
#pragma unroll
    for (int r=0;r<4;++r) {
      int co = mt*16 + kh*4 + r;
      int p  = p0 + n0 + nt*16 + lr;
      float mu = nt ? mu1 : mu0;
      float rs = nt ? rs1 : rs0;
      out[(size_t)(b*64+co)*16384 + p] = (vals[mt][nt][r] - mu)*rs*gamma[co] + beta[co];
    }
    __syncthreads();
  }
}

extern "C" void kernel_launch(void* const* d_in, const int* in_sizes, int n_in,
                              void* d_out, int out_size, void* d_ws, size_t ws_size,
                              hipStream_t stream)
{
  const float* query = (const float*)d_in[0];
  const float* key   = (const float*)d_in[1];
  const float* value = (const float*)d_in[2];
  const float* Wq = (const float*)d_in[3];
  const float* Wk = (const float*)d_in[4];
  const float* Wv = (const float*)d_in[5];
  const float* Wo = (const float*)d_in[6];
  const float* bo = (const float*)d_in[7];
  const float* gamma = (const float*)d_in[8];
  const float* beta  = (const float*)d_in[9];
  char* ws = (char*)d_ws;
  // ws: QKV [0,48MiB) | AO [48,64MiB) — exactly 64 MiB.
  // d_out head: WA (216 KiB) phase-0 scratch; barrier words (2 KiB, line-padded)
  // at +1 MiB (zeroed each call); phase 3 overwrites all of d_out last.
  f16*      QKV  = (f16*)ws;
  f16*      AO   = (f16*)(ws + (size_t)50331648);
  f16*      WA   = (f16*)d_out;
  float*    outp = (float*)d_out;
  unsigned* bar  = (unsigned*)((char*)d_out + (size_t)(1<<20));

  hipMemsetAsync(bar, 0, 2048, stream);
  mega<<<dim3(NBLK), dim3(512), 0, stream>>>(
      query, key, value, Wq, Wk, Wv, Wo, bo, gamma, beta,
      QKV, AO, WA, outp, bar);
}